// Round 3
// baseline (196.363 us; speedup 1.0000x reference)
//
#include <hip/hip_runtime.h>

typedef unsigned short u16;
typedef unsigned int   u32;
typedef __attribute__((ext_vector_type(8))) short          shortx8;
typedef __attribute__((ext_vector_type(8))) unsigned short ushortx8;
typedef __attribute__((ext_vector_type(4))) float          floatx4;

__device__ __forceinline__ float b2f(u16 v) {
  return __uint_as_float(((u32)v) << 16);
}
__device__ __forceinline__ u16 f2b(float f) {
  u32 u = __float_as_uint(f);
  u += 0x7FFF + ((u >> 16) & 1);   // RNE
  return (u16)(u >> 16);
}

__device__ __forceinline__ ushortx8 load8_bf16(const u16* p) {
  return *(const ushortx8*)p;
}
__device__ __forceinline__ ushortx8 load8_f32(const float* p) {
  floatx4 v0 = *(const floatx4*)p;
  floatx4 v1 = *(const floatx4*)(p + 4);
  ushortx8 r;
#pragma unroll
  for (int j = 0; j < 4; ++j) { r[j] = f2b(v0[j]); r[4 + j] = f2b(v1[j]); }
  return r;
}

// ---------------------------------------------------------------------------
// Transpose fp32 -> bf16: out[c][r] = bf16(in[r][c]).  R, C multiples of 32.
__global__ void transpose_cast(const float* __restrict__ in, u16* __restrict__ out,
                               int R, int C) {
  __shared__ u16 tile[32][33];
  const int tx = threadIdx.x & 31;
  const int ty = threadIdx.x >> 5;          // 0..7
  const int cb = blockIdx.x * 32;
  const int rb = blockIdx.y * 32;
#pragma unroll
  for (int i = 0; i < 32; i += 8)
    tile[ty + i][tx] = f2b(in[(size_t)(rb + ty + i) * C + cb + tx]);
  __syncthreads();
#pragma unroll
  for (int i = 0; i < 32; i += 8)
    out[(size_t)(cb + ty + i) * R + rb + tx] = tile[tx][ty + i];
}

// ---------------------------------------------------------------------------
// C[M][N] = A[M][K] @ Bt[N][K]^T.  A: fp32 or bf16 (cast to bf16 at staging),
// Bt: bf16, C: fp32 or bf16.  fp32 accumulate via mfma_f32_16x16x32_bf16.
// 256 threads = 4 waves (2x2), 128x128 tile, BK=32, 4x4 MFMA per wave.
template <typename TA, typename TC>
__global__ __launch_bounds__(256, 2)
void gemm_bt(const TA* __restrict__ A, const u16* __restrict__ Bt,
             TC* __restrict__ C, int M, int N, int K, int lda, int ldc) {
  __shared__ alignas(16) u16 As[128 * 32];
  __shared__ alignas(16) u16 Bs[128 * 32];
  const int tid  = threadIdx.x;
  const int lane = tid & 63;
  const int wave = tid >> 6;
  const int quad = lane >> 4;
  const int lr   = lane & 15;
  const int row0 = blockIdx.x * 128;
  const int col0 = blockIdx.y * 128;
  const int wr   = (wave >> 1) * 64;
  const int wc   = (wave & 1) * 64;

  floatx4 acc[4][4];
#pragma unroll
  for (int i = 0; i < 4; ++i)
#pragma unroll
    for (int j = 0; j < 4; ++j) acc[i][j] = (floatx4)0.0f;

  // staging: chunk c = i*256 + tid covers row c>>2, cols (c&3)*8 .. +7
  const int rr = tid >> 2;
  const int cc = (tid & 3) * 8;
  const TA*  a0 = A  + (size_t)(row0 + rr)      * lda + cc;
  const TA*  a1 = A  + (size_t)(row0 + 64 + rr) * lda + cc;
  const u16* b0 = Bt + (size_t)(col0 + rr)      * K + cc;
  const u16* b1 = Bt + (size_t)(col0 + 64 + rr) * K + cc;
  ushortx8* as0 = (ushortx8*)&As[tid * 8];
  ushortx8* as1 = (ushortx8*)&As[(256 + tid) * 8];
  ushortx8* bs0 = (ushortx8*)&Bs[tid * 8];
  ushortx8* bs1 = (ushortx8*)&Bs[(256 + tid) * 8];

  for (int k0 = 0; k0 < K; k0 += 32) {
    ushortx8 va0, va1;
    if constexpr (sizeof(TA) == 4) {
      va0 = load8_f32((const float*)(a0 + k0));
      va1 = load8_f32((const float*)(a1 + k0));
    } else {
      va0 = load8_bf16((const u16*)(a0 + k0));
      va1 = load8_bf16((const u16*)(a1 + k0));
    }
    ushortx8 vb0 = load8_bf16(b0 + k0);
    ushortx8 vb1 = load8_bf16(b1 + k0);
    *as0 = va0;
    *as1 = va1;
    *bs0 = vb0;
    *bs1 = vb1;
    __syncthreads();

    shortx8 af[4], bf[4];
#pragma unroll
    for (int mi = 0; mi < 4; ++mi)   // A[m=lane&15][k=quad*8+j]
      af[mi] = *(const shortx8*)&As[(wr + mi * 16 + lr) * 32 + quad * 8];
#pragma unroll
    for (int ni = 0; ni < 4; ++ni)   // B[n=lane&15][k=quad*8+j] from Bt rows
      bf[ni] = *(const shortx8*)&Bs[(wc + ni * 16 + lr) * 32 + quad * 8];
#pragma unroll
    for (int mi = 0; mi < 4; ++mi)
#pragma unroll
      for (int ni = 0; ni < 4; ++ni)
        acc[mi][ni] = __builtin_amdgcn_mfma_f32_16x16x32_bf16(
            af[mi], bf[ni], acc[mi][ni], 0, 0, 0);
    __syncthreads();
  }

  // C/D layout: col = lane&15, row = quad*4 + reg  [verified m89/m91]
#pragma unroll
  for (int mi = 0; mi < 4; ++mi)
#pragma unroll
    for (int ni = 0; ni < 4; ++ni)
#pragma unroll
      for (int r = 0; r < 4; ++r) {
        int row = row0 + wr + mi * 16 + quad * 4 + r;
        int col = col0 + wc + ni * 16 + lr;
        float v = acc[mi][ni][r];
        if constexpr (sizeof(TC) == 2)
          C[(size_t)row * ldc + col] = f2b(v);
        else
          C[(size_t)row * ldc + col] = v;
      }
}

// ---------------------------------------------------------------------------
// Local attention, one wave per position. qkv row (bf16, stride 1536) =
// [q(512) k(512) v(512)].  Writes tmp = attn@v_win + v into the (dead)
// q-columns of its OWN row — other waves only read k/v columns, so no race.
__global__ __launch_bounds__(256)
void attn_local(u16* __restrict__ qkv, const float* __restrict__ x,
                const float* __restrict__ w_width,
                const float* __restrict__ b_width) {
  const int lane = threadIdx.x & 63;
  const int gw   = blockIdx.x * 4 + (threadIdx.x >> 6);  // 0..16383
  const int pos  = gw & 8191;
  const int c0   = lane * 8;
  const size_t rq = (size_t)gw * 1536;

  // q chunk (8 channels per lane)
  float q[8];
  {
    ushortx8 t = *(const ushortx8*)(qkv + rq + c0);
#pragma unroll
    for (int j = 0; j < 8; ++j) q[j] = b2f(t[j]);
  }

  // width = sigmoid(x.w_width + b)*16 + 1   (full fp32 path)
  float width;
  {
    const float* xp = x + (size_t)gw * 512 + c0;
    floatx4 x0 = *(const floatx4*)xp;
    floatx4 x1 = *(const floatx4*)(xp + 4);
    floatx4 w0 = *(const floatx4*)(w_width + c0);
    floatx4 w1 = *(const floatx4*)(w_width + c0 + 4);
    float s = 0.f;
#pragma unroll
    for (int j = 0; j < 4; ++j) s += x0[j] * w0[j] + x1[j] * w1[j];
#pragma unroll
    for (int m = 32; m >= 1; m >>= 1) s += __shfl_xor(s, m, 64);
    width = 16.f / (1.f + __expf(-(s + b_width[0]))) + 1.f;
  }

  // raw scores over the 17-wide window (zero-padded edges -> score 0)
  float sc[17];
#pragma unroll
  for (int d = 0; d < 17; ++d) {
    const int src = pos + d - 8;
    float s = 0.f;
    if ((unsigned)src < 8192u) {   // wave-uniform branch
      const u16* kp = qkv + ((ptrdiff_t)rq + (ptrdiff_t)(d - 8) * 1536 + 512 + c0);
      ushortx8 k8 = *(const ushortx8*)kp;
      float p = 0.f;
#pragma unroll
      for (int j = 0; j < 8; ++j) p += q[j] * b2f(k8[j]);
#pragma unroll
      for (int m = 32; m >= 1; m >>= 1) p += __shfl_xor(p, m, 64);
      s = p;
    }
    sc[d] = s;
  }

  // soft mask + softmax (redundant per-lane; all lanes hold identical sc[])
  const float scale = 0.044194173824159216f;   // 512^-0.5
  float mx = -3.4e38f;
#pragma unroll
  for (int d = 0; d < 17; ++d) {
    float rel  = fabsf((float)(d - 8));
    float mask = 1.f / (1.f + __expf(-5.f * (width - rel)));
    float s    = sc[d] * scale - (1.f - mask) * 10000.f;
    sc[d] = s;
    mx = fmaxf(mx, s);
  }
  float sum = 0.f;
#pragma unroll
  for (int d = 0; d < 17; ++d) { float e = __expf(sc[d] - mx); sc[d] = e; sum += e; }
  const float inv = 1.f / sum;

  // out = attn @ v_win + v
  float acc[8];
  {
    ushortx8 v = *(const ushortx8*)(qkv + rq + 1024 + c0);
#pragma unroll
    for (int j = 0; j < 8; ++j) acc[j] = b2f(v[j]);
  }
#pragma unroll
  for (int d = 0; d < 17; ++d) {
    const int src = pos + d - 8;
    if ((unsigned)src < 8192u) {
      const u16* vp = qkv + ((ptrdiff_t)rq + (ptrdiff_t)(d - 8) * 1536 + 1024 + c0);
      ushortx8 v8 = *(const ushortx8*)vp;
      float a = sc[d] * inv;
#pragma unroll
      for (int j = 0; j < 8; ++j) acc[j] += a * b2f(v8[j]);
    }
  }
  ushortx8 o;
#pragma unroll
  for (int j = 0; j < 8; ++j) o[j] = f2b(acc[j]);
  *(ushortx8*)(qkv + rq + c0) = o;   // own-row q columns, read-before-write
}

// ---------------------------------------------------------------------------
extern "C" void kernel_launch(void* const* d_in, const int* in_sizes, int n_in,
                              void* d_out, int out_size, void* d_ws, size_t ws_size,
                              hipStream_t stream) {
  const float* x       = (const float*)d_in[0];  // [2,8192,512] fp32
  const float* w_qkv   = (const float*)d_in[1];  // [512,1536]  fp32
  const float* w_width = (const float*)d_in[2];  // [512,1]     fp32
  const float* b_width = (const float*)d_in[3];  // [1]         fp32
  const float* w_out   = (const float*)d_in[4];  // [512,512]   fp32
  float* out = (float*)d_out;                    // [2,8192,512] fp32

  const int M = 16384, C = 512, N3 = 1536;
  char* ws = (char*)d_ws;
  u16* qkv   = (u16*)(ws);                               // 50,331,648 B
  u16* wqkvT = (u16*)(ws + (size_t)50331648);            //  1,572,864 B
  u16* woutT = (u16*)(ws + (size_t)50331648 + 1572864);  //    524,288 B
  // total 52,428,800 B of d_ws

  dim3 blk(256);
  transpose_cast<<<dim3(N3 / 32, C / 32), blk, 0, stream>>>(w_qkv, wqkvT, C, N3);
  transpose_cast<<<dim3(C / 32, C / 32), blk, 0, stream>>>(w_out, woutT, C, C);
  // qkv = bf16( x @ w_qkv )
  gemm_bt<float, u16><<<dim3(M / 128, N3 / 128), blk, 0, stream>>>(
      x, wqkvT, qkv, M, N3, C, C, N3);
  // q-columns of qkv <- attn output + v
  attn_local<<<dim3(M / 4), blk, 0, stream>>>(qkv, x, w_width, b_width);
  // out = (attn_out + v) @ w_out   (A = q-columns of qkv, lda = 1536)
  gemm_bt<u16, float><<<dim3(M / 128, C / 128), blk, 0, stream>>>(
      qkv, woutT, out, M, C, C, N3, C);
}

// Round 4
// 168.226 us; speedup vs baseline: 1.1673x; 1.1673x over previous
//
#include <hip/hip_runtime.h>

typedef unsigned short u16;
typedef unsigned int   u32;
typedef __attribute__((ext_vector_type(8))) short          shortx8;
typedef __attribute__((ext_vector_type(8))) unsigned short ushortx8;
typedef __attribute__((ext_vector_type(4))) float          floatx4;

#define AS1 __attribute__((address_space(1)))
#define AS3 __attribute__((address_space(3)))

#define SEG 8208   // 8192 + 16 pad cols per batch segment of Vt
#define LV  16416  // 2 * SEG

__device__ __forceinline__ float b2f(u16 v) {
  return __uint_as_float(((u32)v) << 16);
}
__device__ __forceinline__ u16 f2b(float f) {
  u32 u = __float_as_uint(f);
  u += 0x7FFF + ((u >> 16) & 1);   // RNE
  return (u16)(u >> 16);
}
__device__ __forceinline__ void cp16(const void* g, void* l) {
  // 16B/lane global->LDS DMA; LDS dest must be wave-uniform base + lane*16
  __builtin_amdgcn_global_load_lds((AS1 u32*)g, (AS3 u32*)l, 16, 0, 0);
}

// ---------------------------------------------------------------------------
// Transpose fp32 -> bf16: out[c][r] = bf16(in[r][c]).  R, C multiples of 32.
__global__ void transpose_cast(const float* __restrict__ in, u16* __restrict__ out,
                               int R, int C) {
  __shared__ u16 tile[32][33];
  const int tx = threadIdx.x & 31;
  const int ty = threadIdx.x >> 5;
  const int cb = blockIdx.x * 32;
  const int rb = blockIdx.y * 32;
#pragma unroll
  for (int i = 0; i < 32; i += 8)
    tile[ty + i][tx] = f2b(in[(size_t)(rb + ty + i) * C + cb + tx]);
  __syncthreads();
#pragma unroll
  for (int i = 0; i < 32; i += 8)
    out[(size_t)(cb + ty + i) * R + rb + tx] = tile[tx][ty + i];
}

// ---------------------------------------------------------------------------
// Per-row: x_bf16 = bf16(x); width[row] = sigmoid(x.w_width + b)*16 + 1.
// One wave per row, 4 rows per block.
__global__ __launch_bounds__(256)
void cast_width(const float* __restrict__ x, const float* __restrict__ w_width,
                const float* __restrict__ b_width, u16* __restrict__ xb,
                float* __restrict__ width) {
  const int lane = threadIdx.x & 63;
  const int row  = blockIdx.x * 4 + (threadIdx.x >> 6);
  const float* xp = x + (size_t)row * 512 + lane * 8;
  floatx4 v0 = *(const floatx4*)xp;
  floatx4 v1 = *(const floatx4*)(xp + 4);
  floatx4 w0 = *(const floatx4*)(w_width + lane * 8);
  floatx4 w1 = *(const floatx4*)(w_width + lane * 8 + 4);
  float s = 0.f;
  ushortx8 o;
#pragma unroll
  for (int j = 0; j < 4; ++j) {
    s += v0[j] * w0[j] + v1[j] * w1[j];
    o[j] = f2b(v0[j]); o[4 + j] = f2b(v1[j]);
  }
  *(ushortx8*)(xb + (size_t)row * 512 + lane * 8) = o;
#pragma unroll
  for (int m = 32; m >= 1; m >>= 1) s += __shfl_xor(s, m, 64);
  if (lane == 0)
    width[row] = 16.f / (1.f + __expf(-(s + b_width[0]))) + 1.f;
}

// ---------------------------------------------------------------------------
// Zero the pad columns of Vt (cols 0..7 and 8200..8207 of each batch segment).
__global__ void vt_zero_pad(u16* __restrict__ Vt) {
  const int idx = blockIdx.x * 256 + threadIdx.x;  // 512 ch * 32 pad cols
  const int ch = idx >> 5;
  const int k  = idx & 31;
  const int seg = k >> 4;
  const int j   = k & 15;
  const int col = seg * SEG + (j < 8 ? j : 8192 + j);
  Vt[(size_t)ch * LV + col] = 0;
}

// ---------------------------------------------------------------------------
// C = A[M][512] @ Bt[N][512]^T, bf16 in, fp32 acc.  m97 structure:
// 128x128 tile, BK=32, 4 waves 2x2, global_load_lds width=16.
// MODE 1: N=1536, scatter epilogue -> Qb / Kb / Vt(transposed, batch-padded).
// MODE 2: N=512,  fp32 C (ldc=512).
template <int MODE>
__global__ __launch_bounds__(256, 2)
void gemm_bt(const u16* __restrict__ A, const u16* __restrict__ Bt,
             void* __restrict__ C0, u16* __restrict__ Kb, u16* __restrict__ Vt) {
  const int K = 512;
  __shared__ alignas(16) u16 As[128 * 32];
  __shared__ alignas(16) u16 Bs[128 * 32];
  const int tid  = threadIdx.x;
  const int lane = tid & 63;
  const int wave = tid >> 6;
  const int quad = lane >> 4;
  const int lr   = lane & 15;
  const int row0 = blockIdx.x * 128;
  const int col0 = blockIdx.y * 128;
  const int wr   = (wave >> 1) * 64;
  const int wc   = (wave & 1) * 64;

  floatx4 acc[4][4];
#pragma unroll
  for (int i = 0; i < 4; ++i)
#pragma unroll
    for (int j = 0; j < 4; ++j) acc[i][j] = (floatx4)0.0f;

  const int rr = tid >> 2;
  const int cc = (tid & 3) * 8;
  const u16* a0 = A  + (size_t)(row0 + rr)      * K + cc;
  const u16* a1 = A  + (size_t)(row0 + 64 + rr) * K + cc;
  const u16* b0 = Bt + (size_t)(col0 + rr)      * K + cc;
  const u16* b1 = Bt + (size_t)(col0 + 64 + rr) * K + cc;
  u16* as0 = &As[tid * 8];
  u16* as1 = &As[(256 + tid) * 8];
  u16* bs0 = &Bs[tid * 8];
  u16* bs1 = &Bs[(256 + tid) * 8];

  for (int k0 = 0; k0 < K; k0 += 32) {
    cp16(a0 + k0, as0);
    cp16(a1 + k0, as1);
    cp16(b0 + k0, bs0);
    cp16(b1 + k0, bs1);
    __syncthreads();   // drains vmcnt(0)

    shortx8 af[4], bf[4];
#pragma unroll
    for (int mi = 0; mi < 4; ++mi)   // A[m=lane&15][k=quad*8+j]
      af[mi] = *(const shortx8*)&As[(wr + mi * 16 + lr) * 32 + quad * 8];
#pragma unroll
    for (int ni = 0; ni < 4; ++ni)
      bf[ni] = *(const shortx8*)&Bs[(wc + ni * 16 + lr) * 32 + quad * 8];
#pragma unroll
    for (int mi = 0; mi < 4; ++mi)
#pragma unroll
      for (int ni = 0; ni < 4; ++ni)
        acc[mi][ni] = __builtin_amdgcn_mfma_f32_16x16x32_bf16(
            af[mi], bf[ni], acc[mi][ni], 0, 0, 0);
    __syncthreads();
  }

  // C/D layout: col = lane&15, row = quad*4 + reg  [verified m89/m91]
  if constexpr (MODE == 1) {
    if (col0 < 1024) {               // Q or K section (wave-uniform branch)
      u16* dst = (col0 < 512) ? (u16*)C0 : Kb;
      const int cb = col0 & 511;
#pragma unroll
      for (int mi = 0; mi < 4; ++mi)
#pragma unroll
        for (int ni = 0; ni < 4; ++ni)
#pragma unroll
          for (int r = 0; r < 4; ++r) {
            int row = row0 + wr + mi * 16 + quad * 4 + r;
            int col = cb + wc + ni * 16 + lr;
            dst[(size_t)row * 512 + col] = f2b(acc[mi][ni][r]);
          }
    } else {                         // V section -> transposed, batch-padded
      const int cb = col0 - 1024;
#pragma unroll
      for (int mi = 0; mi < 4; ++mi)
#pragma unroll
        for (int ni = 0; ni < 4; ++ni)
#pragma unroll
          for (int r = 0; r < 4; ++r) {
            int row = row0 + wr + mi * 16 + quad * 4 + r;
            int ch  = cb + wc + ni * 16 + lr;
            int bb  = row >> 13, pib = row & 8191;
            Vt[(size_t)ch * LV + (size_t)bb * SEG + 8 + pib] = f2b(acc[mi][ni][r]);
          }
    }
  } else {
    float* Cf = (float*)C0;
#pragma unroll
    for (int mi = 0; mi < 4; ++mi)
#pragma unroll
      for (int ni = 0; ni < 4; ++ni)
#pragma unroll
        for (int r = 0; r < 4; ++r) {
          int row = row0 + wr + mi * 16 + quad * 4 + r;
          int col = col0 + wc + ni * 16 + lr;
          Cf[(size_t)row * 512 + col] = acc[mi][ni][r];
        }
  }
}

// ---------------------------------------------------------------------------
// MFMA local attention. Block = 16 positions (p0 = blockIdx.x*16), 4 waves.
// Phase A: S[16x32] = Q_tile . K_window^T, split-K over waves (128 ch each).
// Phase B: masked softmax (band + batch predicates), P(+I at d=8) -> LDS bf16.
// Phase C: O[16x512] = P . V_window via Vt, waves split channels; store -> Q.
__global__ __launch_bounds__(256)
void attn_mfma(const u16* __restrict__ Q, const u16* __restrict__ Kb,
               const u16* __restrict__ Vt, const float* __restrict__ width,
               u16* __restrict__ Out) {
  __shared__ float Sp[8][16][16];   // [wave*2+t][row][lr]
  __shared__ u16   P[16][32];       // A-layout for PV
  __shared__ u16   O[4][16][128];   // per-wave C->row-major shuffle
  const int tid  = threadIdx.x;
  const int lane = tid & 63;
  const int wave = tid >> 6;
  const int quad = lane >> 4;
  const int lr   = lane & 15;
  const int p0   = blockIdx.x * 16;
  const int pib0 = p0 & 8191;
  const int bb   = p0 >> 13;

  // ---- Phase A: partial scores over this wave's 128-channel chunk
  floatx4 s0 = (floatx4)0.0f, s1 = (floatx4)0.0f;
#pragma unroll
  for (int s = 0; s < 4; ++s) {
    const int k0 = wave * 128 + s * 32 + quad * 8;
    shortx8 af = *(const shortx8*)(Q  + (size_t)(p0 + lr) * 512 + k0);
    shortx8 f0 = *(const shortx8*)(Kb + (ptrdiff_t)(p0 - 8 + lr) * 512 + k0);
    shortx8 f1 = *(const shortx8*)(Kb + (ptrdiff_t)(p0 + 8 + lr) * 512 + k0);
    s0 = __builtin_amdgcn_mfma_f32_16x16x32_bf16(af, f0, s0, 0, 0, 0);
    s1 = __builtin_amdgcn_mfma_f32_16x16x32_bf16(af, f1, s1, 0, 0, 0);
  }
#pragma unroll
  for (int r = 0; r < 4; ++r) {
    Sp[wave * 2 + 0][quad * 4 + r][lr] = s0[r];
    Sp[wave * 2 + 1][quad * 4 + r][lr] = s1[r];
  }
  __syncthreads();

  // ---- Phase B: softmax. thread -> row=tid>>4, cols {cg, cg+16}
  {
    const int row = tid >> 4, cg = tid & 15;
    const float scale = 0.044194173824159216f;   // 512^-0.5
    const float wrow  = width[p0 + row];
    float sv[2]; float mx = -1e30f;
#pragma unroll
    for (int t = 0; t < 2; ++t) {
      const int col = t * 16 + cg;
      float s = Sp[t][row][cg] + Sp[2 + t][row][cg] +
                Sp[4 + t][row][cg] + Sp[6 + t][row][cg];
      const int d  = col - row;           // window slot 0..16 when in band
      const int jb = pib0 + col - 8;      // position within batch
      const bool inband  = (d >= 0) && (d <= 16);
      const bool inbatch = ((unsigned)jb < 8192u);
      float rel  = fabsf((float)(d - 8));
      float mask = 1.f / (1.f + __expf(-5.f * (wrow - rel)));
      float pen  = (1.f - mask) * 10000.f;
      float val  = inband ? ((inbatch ? s * scale : 0.f) - pen) : -1e30f;
      sv[t] = val;
      mx = fmaxf(mx, val);
    }
#pragma unroll
    for (int m = 8; m >= 1; m >>= 1) mx = fmaxf(mx, __shfl_xor(mx, m, 64));
    float e0 = __expf(sv[0] - mx), e1 = __expf(sv[1] - mx);
    float sum = e0 + e1;
#pragma unroll
    for (int m = 8; m >= 1; m >>= 1) sum += __shfl_xor(sum, m, 64);
    const float inv = 1.f / sum;
    // +1 at the self slot (d==8) folds the "+ v" into PV
    P[row][cg]      = f2b(e0 * inv + ((cg - row) == 8 ? 1.f : 0.f));
    P[row][cg + 16] = f2b(e1 * inv + ((cg + 16 - row) == 8 ? 1.f : 0.f));
  }
  __syncthreads();

  // ---- Phase C: PV over this wave's 128 channels
  shortx8 pf = *(const shortx8*)&P[lr][quad * 8];   // A[m=lr][k=quad*8+j]
  const size_t cb0 = (size_t)bb * SEG + pib0;       // Vt col of j_local=0
#pragma unroll
  for (int ct = 0; ct < 8; ++ct) {
    const int ch = wave * 128 + ct * 16 + lr;
    shortx8 vf = *(const shortx8*)(Vt + (size_t)ch * LV + cb0 + quad * 8);
    floatx4 o = __builtin_amdgcn_mfma_f32_16x16x32_bf16(pf, vf, (floatx4)0.0f,
                                                        0, 0, 0);
#pragma unroll
    for (int r = 0; r < 4; ++r)
      O[wave][quad * 4 + r][ct * 16 + lr] = f2b(o[r]);
  }
  __syncthreads();
  {
    const int orow = lane >> 2;
#pragma unroll
    for (int i = 0; i < 4; ++i) {
      const int c = i * 32 + (lane & 3) * 8;
      ushortx8 v = *(const ushortx8*)&O[wave][orow][c];
      *(ushortx8*)(Out + (size_t)(p0 + orow) * 512 + wave * 128 + c) = v;
    }
  }
}

// ---------------------------------------------------------------------------
extern "C" void kernel_launch(void* const* d_in, const int* in_sizes, int n_in,
                              void* d_out, int out_size, void* d_ws, size_t ws_size,
                              hipStream_t stream) {
  const float* x       = (const float*)d_in[0];  // [2,8192,512] fp32
  const float* w_qkv   = (const float*)d_in[1];  // [512,1536]  fp32
  const float* w_width = (const float*)d_in[2];  // [512,1]     fp32
  const float* b_width = (const float*)d_in[3];  // [1]         fp32
  const float* w_out   = (const float*)d_in[4];  // [512,512]   fp32
  float* out = (float*)d_out;                    // [2,8192,512] fp32

  const int M = 16384, C = 512, N3 = 1536;
  char* ws = (char*)d_ws;
  u16*   xb    = (u16*)(ws);                       // 16,777,216
  u16*   Qb    = (u16*)(ws + 16777216);            // 16,777,216
  u16*   Kb    = (u16*)(ws + 33554432 + 8192);     // 8KB guard | 16,777,216 | 8KB guard
  u16*   Vt    = (u16*)(ws + 50348032);            // 512*16416*2 = 16,809,984
  u16*   wqkvT = (u16*)(ws + 67158016);            //  1,572,864
  u16*   woutT = (u16*)(ws + 68730880);            //    524,288
  float* width = (float*)(ws + 69255168);          //     65,536   (total ~69.3 MB)

  dim3 blk(256);
  vt_zero_pad<<<dim3(64), blk, 0, stream>>>(Vt);
  cast_width<<<dim3(M / 4), blk, 0, stream>>>(x, w_width, b_width, xb, width);
  transpose_cast<<<dim3(N3 / 32, C / 32), blk, 0, stream>>>(w_qkv, wqkvT, C, N3);
  transpose_cast<<<dim3(C / 32, C / 32), blk, 0, stream>>>(w_out, woutT, C, C);
  // xb @ w_qkv -> split Q / K(guarded) / Vt(transposed, padded)
  gemm_bt<1><<<dim3(M / 128, N3 / 128), blk, 0, stream>>>(xb, wqkvT, Qb, Kb, Vt);
  // attention; result (attn@v + v) overwrites Q rows
  attn_mfma<<<dim3(M / 16), blk, 0, stream>>>(Qb, Kb, Vt, width, Qb);
  // (attn_out + v) @ w_out -> fp32 out
  gemm_bt<2><<<dim3(M / 128, C / 128), blk, 0, stream>>>(Qb, woutT, out, nullptr, nullptr);
}

// Round 5
// 160.511 us; speedup vs baseline: 1.2234x; 1.0481x over previous
//
#include <hip/hip_runtime.h>

typedef unsigned short u16;
typedef unsigned int   u32;
typedef __attribute__((ext_vector_type(8))) short          shortx8;
typedef __attribute__((ext_vector_type(8))) unsigned short ushortx8;
typedef __attribute__((ext_vector_type(4))) float          floatx4;

#define AS1 __attribute__((address_space(1)))
#define AS3 __attribute__((address_space(3)))

#define SEG 8208   // 8192 + 16 pad cols per batch segment of Vt
#define LV  16416  // 2 * SEG

__device__ __forceinline__ float b2f(u16 v) {
  return __uint_as_float(((u32)v) << 16);
}
__device__ __forceinline__ u16 f2b(float f) {
  u32 u = __float_as_uint(f);
  u += 0x7FFF + ((u >> 16) & 1);   // RNE
  return (u16)(u >> 16);
}
__device__ __forceinline__ void cp16(const void* g, void* l) {
  // 16B/lane global->LDS DMA; LDS dest must be wave-uniform base + lane*16
  __builtin_amdgcn_global_load_lds((AS1 u32*)g, (AS3 u32*)l, 16, 0, 0);
}

// ---------------------------------------------------------------------------
// Transpose fp32 -> bf16: out[c][r] = bf16(in[r][c]).  R, C multiples of 32.
__global__ void transpose_cast(const float* __restrict__ in, u16* __restrict__ out,
                               int R, int C) {
  __shared__ u16 tile[32][33];
  const int tx = threadIdx.x & 31;
  const int ty = threadIdx.x >> 5;
  const int cb = blockIdx.x * 32;
  const int rb = blockIdx.y * 32;
#pragma unroll
  for (int i = 0; i < 32; i += 8)
    tile[ty + i][tx] = f2b(in[(size_t)(rb + ty + i) * C + cb + tx]);
  __syncthreads();
#pragma unroll
  for (int i = 0; i < 32; i += 8)
    out[(size_t)(cb + ty + i) * R + rb + tx] = tile[tx][ty + i];
}

// ---------------------------------------------------------------------------
// Per-row: x_bf16 = bf16(x); width[row] = sigmoid(x.w_width + b)*16 + 1.
__global__ __launch_bounds__(256)
void cast_width(const float* __restrict__ x, const float* __restrict__ w_width,
                const float* __restrict__ b_width, u16* __restrict__ xb,
                float* __restrict__ width) {
  const int lane = threadIdx.x & 63;
  const int row  = blockIdx.x * 4 + (threadIdx.x >> 6);
  const float* xp = x + (size_t)row * 512 + lane * 8;
  floatx4 v0 = *(const floatx4*)xp;
  floatx4 v1 = *(const floatx4*)(xp + 4);
  floatx4 w0 = *(const floatx4*)(w_width + lane * 8);
  floatx4 w1 = *(const floatx4*)(w_width + lane * 8 + 4);
  float s = 0.f;
  ushortx8 o;
#pragma unroll
  for (int j = 0; j < 4; ++j) {
    s += v0[j] * w0[j] + v1[j] * w1[j];
    o[j] = f2b(v0[j]); o[4 + j] = f2b(v1[j]);
  }
  *(ushortx8*)(xb + (size_t)row * 512 + lane * 8) = o;
#pragma unroll
  for (int m = 32; m >= 1; m >>= 1) s += __shfl_xor(s, m, 64);
  if (lane == 0)
    width[row] = 16.f / (1.f + __expf(-(s + b_width[0]))) + 1.f;
}

// ---------------------------------------------------------------------------
// Zero the pad columns of Vt (cols 0..7 and 8200..8207 of each batch segment).
__global__ void vt_zero_pad(u16* __restrict__ Vt) {
  const int idx = blockIdx.x * 256 + threadIdx.x;  // 512 ch * 32 pad cols
  const int ch = idx >> 5;
  const int k  = idx & 31;
  const int seg = k >> 4;
  const int j   = k & 15;
  const int col = seg * SEG + (j < 8 ? j : 8192 + j);
  Vt[(size_t)ch * LV + col] = 0;
}

// ---------------------------------------------------------------------------
// C = A[M][512] @ Bt[N][512]^T, bf16 in, fp32 acc.  128x128 tile, BK=64,
// XOR-swizzled LDS staging (conflict-free ds_read_b128), LDS-shuffled
// coalesced epilogues.  4 waves 2x2, 4x4 x 2 MFMA per wave per iter.
// MODE 1: N=1536, scatter epilogue -> Qb / Kb / Vt(transposed, batch-padded).
// MODE 2: N=512,  fp32 C (ldc=512), direct stores.
template <int MODE>
__global__ __launch_bounds__(256, 2)
void gemm_bt(const u16* __restrict__ A, const u16* __restrict__ Bt,
             void* __restrict__ C0, u16* __restrict__ Kb, u16* __restrict__ Vt) {
  const int K = 512;
  __shared__ alignas(16) u16 lds[17408];        // 34,816 B (union)
  u16* As = lds;                                // 8192 u16 (128 x 64)
  u16* Bs = lds + 8192;                         // 8192 u16
  const int tid  = threadIdx.x;
  const int lane = tid & 63;
  const int wave = tid >> 6;
  const int quad = lane >> 4;
  const int lr   = lane & 15;
  const int row0 = blockIdx.x * 128;
  const int col0 = blockIdx.y * 128;
  const int wr   = (wave >> 1) * 64;
  const int wc   = (wave & 1) * 64;

  floatx4 acc[4][4];
#pragma unroll
  for (int i = 0; i < 4; ++i)
#pragma unroll
    for (int j = 0; j < 4; ++j) acc[i][j] = (floatx4)0.0f;

  // Staging map: chunk c = p*256+tid -> LDS slot c (16B each); covers
  // (row = c>>3, phys colblk = c&7) which holds GLOBAL colblk (c&7)^(row&7).
  int srow[4], scol[4];
#pragma unroll
  for (int p = 0; p < 4; ++p) {
    int c = p * 256 + tid;
    srow[p] = c >> 3;
    scol[p] = ((c & 7) ^ (srow[p] & 7)) * 8;
  }
  const int swz = lr & 7;   // reader un-swizzle key (row & 7 == lr & 7)

  for (int k0 = 0; k0 < K; k0 += 64) {
#pragma unroll
    for (int p = 0; p < 4; ++p)
      cp16(A + (size_t)(row0 + srow[p]) * K + k0 + scol[p], &As[(p * 256 + tid) * 8]);
#pragma unroll
    for (int p = 0; p < 4; ++p)
      cp16(Bt + (size_t)(col0 + srow[p]) * K + k0 + scol[p], &Bs[(p * 256 + tid) * 8]);
    __syncthreads();   // drains vmcnt(0)

#pragma unroll
    for (int ks = 0; ks < 2; ++ks) {
      shortx8 af[4], bf[4];
#pragma unroll
      for (int mi = 0; mi < 4; ++mi)
        af[mi] = *(const shortx8*)
            &As[((wr + mi * 16 + lr) * 8 + ((ks * 4 + quad) ^ swz)) * 8];
#pragma unroll
      for (int ni = 0; ni < 4; ++ni)
        bf[ni] = *(const shortx8*)
            &Bs[((wc + ni * 16 + lr) * 8 + ((ks * 4 + quad) ^ swz)) * 8];
#pragma unroll
      for (int mi = 0; mi < 4; ++mi)
#pragma unroll
        for (int ni = 0; ni < 4; ++ni)
          acc[mi][ni] = __builtin_amdgcn_mfma_f32_16x16x32_bf16(
              af[mi], bf[ni], acc[mi][ni], 0, 0, 0);
    }
    __syncthreads();
  }

  // C/D layout: col = lane&15, row = quad*4 + reg  [verified m89/m91]
  if constexpr (MODE == 1) {
    if (col0 < 1024) {               // ---- Q or K: row-major LDS, coalesced out
      u16* dst = (col0 < 512) ? (u16*)C0 : Kb;
      const int cb = col0 & 511;
#pragma unroll
      for (int mi = 0; mi < 4; ++mi)
#pragma unroll
        for (int ni = 0; ni < 4; ++ni)
#pragma unroll
          for (int r = 0; r < 4; ++r)
            lds[(wr + mi * 16 + quad * 4 + r) * 136 + wc + ni * 16 + lr] =
                f2b(acc[mi][ni][r]);
      __syncthreads();
      const int rr = tid >> 4, cc = (tid & 15) * 8;
#pragma unroll
      for (int it = 0; it < 8; ++it) {
        int row = it * 16 + rr;
        *(ushortx8*)(dst + (size_t)(row0 + row) * 512 + cb + cc) =
            *(const ushortx8*)&lds[row * 136 + cc];
      }
    } else {                         // ---- V: transposed LDS, coalesced out
      const int cb = col0 - 1024;
      const int bb = row0 >> 13, pib0 = row0 & 8191;
#pragma unroll
      for (int mi = 0; mi < 4; ++mi)
#pragma unroll
        for (int ni = 0; ni < 4; ++ni)
#pragma unroll
          for (int r = 0; r < 4; ++r)
            lds[(wc + ni * 16 + lr) * 136 + wr + mi * 16 + quad * 4 + r] =
                f2b(acc[mi][ni][r]);
      __syncthreads();
      const int rr = tid >> 4, cc = (tid & 15) * 8;
#pragma unroll
      for (int it = 0; it < 8; ++it) {
        int chl = it * 16 + rr;
        ushortx8 v = *(const ushortx8*)&lds[chl * 136 + cc];
        *(ushortx8*)(Vt + (size_t)(cb + chl) * LV + (size_t)bb * SEG + 8 + pib0 + cc) = v;
      }
    }
  } else {
    float* Cf = (float*)C0;
#pragma unroll
    for (int mi = 0; mi < 4; ++mi)
#pragma unroll
      for (int ni = 0; ni < 4; ++ni)
#pragma unroll
        for (int r = 0; r < 4; ++r) {
          int row = row0 + wr + mi * 16 + quad * 4 + r;
          int col = col0 + wc + ni * 16 + lr;
          Cf[(size_t)row * 512 + col] = acc[mi][ni][r];
        }
  }
}

// ---------------------------------------------------------------------------
// MFMA local attention. Block = 16 positions, 4 waves (unchanged from R4).
__global__ __launch_bounds__(256)
void attn_mfma(const u16* __restrict__ Q, const u16* __restrict__ Kb,
               const u16* __restrict__ Vt, const float* __restrict__ width,
               u16* __restrict__ Out) {
  __shared__ float Sp[8][16][16];
  __shared__ u16   P[16][32];
  __shared__ u16   O[4][16][128];
  const int tid  = threadIdx.x;
  const int lane = tid & 63;
  const int wave = tid >> 6;
  const int quad = lane >> 4;
  const int lr   = lane & 15;
  const int p0   = blockIdx.x * 16;
  const int pib0 = p0 & 8191;
  const int bb   = p0 >> 13;

  floatx4 s0 = (floatx4)0.0f, s1 = (floatx4)0.0f;
#pragma unroll
  for (int s = 0; s < 4; ++s) {
    const int k0 = wave * 128 + s * 32 + quad * 8;
    shortx8 af = *(const shortx8*)(Q  + (size_t)(p0 + lr) * 512 + k0);
    shortx8 f0 = *(const shortx8*)(Kb + (ptrdiff_t)(p0 - 8 + lr) * 512 + k0);
    shortx8 f1 = *(const shortx8*)(Kb + (ptrdiff_t)(p0 + 8 + lr) * 512 + k0);
    s0 = __builtin_amdgcn_mfma_f32_16x16x32_bf16(af, f0, s0, 0, 0, 0);
    s1 = __builtin_amdgcn_mfma_f32_16x16x32_bf16(af, f1, s1, 0, 0, 0);
  }
#pragma unroll
  for (int r = 0; r < 4; ++r) {
    Sp[wave * 2 + 0][quad * 4 + r][lr] = s0[r];
    Sp[wave * 2 + 1][quad * 4 + r][lr] = s1[r];
  }
  __syncthreads();

  {
    const int row = tid >> 4, cg = tid & 15;
    const float scale = 0.044194173824159216f;   // 512^-0.5
    const float wrow  = width[p0 + row];
    float sv[2]; float mx = -1e30f;
#pragma unroll
    for (int t = 0; t < 2; ++t) {
      const int col = t * 16 + cg;
      float s = Sp[t][row][cg] + Sp[2 + t][row][cg] +
                Sp[4 + t][row][cg] + Sp[6 + t][row][cg];
      const int d  = col - row;
      const int jb = pib0 + col - 8;
      const bool inband  = (d >= 0) && (d <= 16);
      const bool inbatch = ((unsigned)jb < 8192u);
      float rel  = fabsf((float)(d - 8));
      float mask = 1.f / (1.f + __expf(-5.f * (wrow - rel)));
      float pen  = (1.f - mask) * 10000.f;
      float val  = inband ? ((inbatch ? s * scale : 0.f) - pen) : -1e30f;
      sv[t] = val;
      mx = fmaxf(mx, val);
    }
#pragma unroll
    for (int m = 8; m >= 1; m >>= 1) mx = fmaxf(mx, __shfl_xor(mx, m, 64));
    float e0 = __expf(sv[0] - mx), e1 = __expf(sv[1] - mx);
    float sum = e0 + e1;
#pragma unroll
    for (int m = 8; m >= 1; m >>= 1) sum += __shfl_xor(sum, m, 64);
    const float inv = 1.f / sum;
    P[row][cg]      = f2b(e0 * inv + ((cg - row) == 8 ? 1.f : 0.f));
    P[row][cg + 16] = f2b(e1 * inv + ((cg + 16 - row) == 8 ? 1.f : 0.f));
  }
  __syncthreads();

  shortx8 pf = *(const shortx8*)&P[lr][quad * 8];
  const size_t cb0 = (size_t)bb * SEG + pib0;
#pragma unroll
  for (int ct = 0; ct < 8; ++ct) {
    const int ch = wave * 128 + ct * 16 + lr;
    shortx8 vf = *(const shortx8*)(Vt + (size_t)ch * LV + cb0 + quad * 8);
    floatx4 o = __builtin_amdgcn_mfma_f32_16x16x32_bf16(pf, vf, (floatx4)0.0f,
                                                        0, 0, 0);
#pragma unroll
    for (int r = 0; r < 4; ++r)
      O[wave][quad * 4 + r][ct * 16 + lr] = f2b(o[r]);
  }
  __syncthreads();
  {
    const int orow = lane >> 2;
#pragma unroll
    for (int i = 0; i < 4; ++i) {
      const int c = i * 32 + (lane & 3) * 8;
      ushortx8 v = *(const ushortx8*)&O[wave][orow][c];
      *(ushortx8*)(Out + (size_t)(p0 + orow) * 512 + wave * 128 + c) = v;
    }
  }
}

// ---------------------------------------------------------------------------
extern "C" void kernel_launch(void* const* d_in, const int* in_sizes, int n_in,
                              void* d_out, int out_size, void* d_ws, size_t ws_size,
                              hipStream_t stream) {
  const float* x       = (const float*)d_in[0];  // [2,8192,512] fp32
  const float* w_qkv   = (const float*)d_in[1];  // [512,1536]  fp32
  const float* w_width = (const float*)d_in[2];  // [512,1]     fp32
  const float* b_width = (const float*)d_in[3];  // [1]         fp32
  const float* w_out   = (const float*)d_in[4];  // [512,512]   fp32
  float* out = (float*)d_out;                    // [2,8192,512] fp32

  const int M = 16384, C = 512, N3 = 1536;
  char* ws = (char*)d_ws;
  u16*   xb    = (u16*)(ws);                       // 16,777,216
  u16*   Qb    = (u16*)(ws + 16777216);            // 16,777,216
  u16*   Kb    = (u16*)(ws + 33554432 + 8192);     // 8KB guard | 16.7MB | guard
  u16*   Vt    = (u16*)(ws + 50348032);            // 512*16416*2 = 16,809,984
  u16*   wqkvT = (u16*)(ws + 67158016);            //  1,572,864
  u16*   woutT = (u16*)(ws + 68730880);            //    524,288
  float* width = (float*)(ws + 69255168);          //     65,536

  dim3 blk(256);
  vt_zero_pad<<<dim3(64), blk, 0, stream>>>(Vt);
  cast_width<<<dim3(M / 4), blk, 0, stream>>>(x, w_width, b_width, xb, width);
  transpose_cast<<<dim3(N3 / 32, C / 32), blk, 0, stream>>>(w_qkv, wqkvT, C, N3);
  transpose_cast<<<dim3(C / 32, C / 32), blk, 0, stream>>>(w_out, woutT, C, C);
  gemm_bt<1><<<dim3(M / 128, N3 / 128), blk, 0, stream>>>(xb, wqkvT, Qb, Kb, Vt);
  attn_mfma<<<dim3(M / 16), blk, 0, stream>>>(Qb, Kb, Vt, width, Qb);
  gemm_bt<2><<<dim3(M / 128, C / 128), blk, 0, stream>>>(Qb, woutT, out, nullptr, nullptr);
}